// Round 1
// baseline (284.237 us; speedup 1.0000x reference)
//
#include <hip/hip_runtime.h>
#include <math.h>

#define MARGIN 0.5f
#define D 256          // row length (floats)
#define WAVES_PER_BLOCK 4

__global__ void zero_out_kernel(float* out) {
    out[0] = 0.0f;
}

__global__ __launch_bounds__(256) void pair_loss_kernel(
    const float* __restrict__ h,
    const int* __restrict__ pos,
    const int* __restrict__ neg,
    float* __restrict__ out,
    int P)
{
    const int lane = threadIdx.x & 63;
    const int wave_in_block = threadIdx.x >> 6;
    const int wave_id = blockIdx.x * WAVES_PER_BLOCK + wave_in_block;
    const int nwaves = gridDim.x * WAVES_PER_BLOCK;
    const int total = 2 * P;

    float acc = 0.0f;

    for (int p = wave_id; p < total; p += nwaves) {
        const bool is_neg = (p >= P);
        const int pi = is_neg ? (p - P) : p;
        const int* __restrict__ pr = is_neg ? neg : pos;

        // wave-uniform index loads (compiler scalarizes these)
        const int i = pr[2 * pi];
        const int j = pr[2 * pi + 1];

        const float4* __restrict__ ra =
            (const float4*)(h + (long long)i * D);
        const float4* __restrict__ rb =
            (const float4*)(h + (long long)j * D);

        // lane l covers elements [4l, 4l+4): 64 lanes * 4 = 256 = D
        float4 a = ra[lane];
        float4 b = rb[lane];
        float dx = a.x - b.x;
        float dy = a.y - b.y;
        float dz = a.z - b.z;
        float dw = a.w - b.w;
        float s = dx * dx + dy * dy + dz * dz + dw * dw;

        // 64-lane butterfly reduction; all lanes end with the total
        #pragma unroll
        for (int off = 32; off; off >>= 1)
            s += __shfl_xor(s, off, 64);

        float dist = sqrtf(s);
        float contrib = is_neg ? fmaxf(0.0f, MARGIN - dist) : dist;
        acc += contrib;   // replicated identically across the wave
    }

    // block reduction: lane 0 of each wave contributes
    __shared__ float wsum[WAVES_PER_BLOCK];
    if (lane == 0) wsum[wave_in_block] = acc;
    __syncthreads();
    if (threadIdx.x == 0) {
        float t = 0.0f;
        #pragma unroll
        for (int w = 0; w < WAVES_PER_BLOCK; ++w) t += wsum[w];
        atomicAdd(out, t);
    }
}

extern "C" void kernel_launch(void* const* d_in, const int* in_sizes, int n_in,
                              void* d_out, int out_size, void* d_ws, size_t ws_size,
                              hipStream_t stream) {
    const float* h = (const float*)d_in[0];
    const int* pos = (const int*)d_in[1];
    const int* neg = (const int*)d_in[2];
    float* out = (float*)d_out;

    const int P = in_sizes[1] / 2;   // 200000 pairs each

    // d_out is poisoned with 0xAA before every timed replay — zero it first.
    zero_out_kernel<<<1, 1, 0, stream>>>(out);

    // 2P waves of work total; grid-stride with enough blocks to saturate
    // 256 CUs while amortizing per-pair launch cost.
    int total_waves = 2 * P;                         // 400000
    int blocks = (total_waves + WAVES_PER_BLOCK - 1) / WAVES_PER_BLOCK;
    if (blocks > 8192) blocks = 8192;                // ~12 pairs per wave

    pair_loss_kernel<<<blocks, 256, 0, stream>>>(h, pos, neg, out, P);
}

// Round 2
// 245.306 us; speedup vs baseline: 1.1587x; 1.1587x over previous
//
#include <hip/hip_runtime.h>
#include <math.h>

#define MARGIN 0.5f
#define D 256                 // row length (floats)
#define WAVES_PER_BLOCK 4
#define PAIRS_PER_WAVE 4      // 16 lanes per pair -> 4 pairs per wave per iter

__global__ void zero_out_kernel(float* out) {
    out[0] = 0.0f;
}

__global__ __launch_bounds__(256) void pair_loss_kernel(
    const float* __restrict__ h,
    const int* __restrict__ pos,
    const int* __restrict__ neg,
    float* __restrict__ out,
    int P)
{
    const int lane = threadIdx.x & 63;
    const int g    = lane >> 4;     // pair-group 0..3 within the wave
    const int t    = lane & 15;     // lane within the 16-lane group
    const int wave_in_block = threadIdx.x >> 6;
    const int wave_id = blockIdx.x * WAVES_PER_BLOCK + wave_in_block;
    const int nwaves  = gridDim.x * WAVES_PER_BLOCK;
    const int total   = 2 * P;
    const int stride  = nwaves * PAIRS_PER_WAVE;

    float acc = 0.0f;

    for (int base = wave_id * PAIRS_PER_WAVE; base < total; base += stride) {
        const int p = base + g;
        const bool valid = (p < total);
        float s = 0.0f;
        bool is_neg = false;

        if (valid) {
            is_neg = (p >= P);
            const int pi = is_neg ? (p - P) : p;
            const int2* __restrict__ pairs = (const int2*)(is_neg ? neg : pos);
            const int2 ij = pairs[pi];

            const float4* __restrict__ ra = (const float4*)(h + (long long)ij.x * D);
            const float4* __restrict__ rb = (const float4*)(h + (long long)ij.y * D);

            // 16 lanes x 4 float4 = 256 floats per row; 8 loads in flight/lane
            float4 a0 = ra[t];      float4 b0 = rb[t];
            float4 a1 = ra[t + 16]; float4 b1 = rb[t + 16];
            float4 a2 = ra[t + 32]; float4 b2 = rb[t + 32];
            float4 a3 = ra[t + 48]; float4 b3 = rb[t + 48];

            float dx, dy, dz, dw;
            dx = a0.x - b0.x; dy = a0.y - b0.y; dz = a0.z - b0.z; dw = a0.w - b0.w;
            s += dx * dx + dy * dy + dz * dz + dw * dw;
            dx = a1.x - b1.x; dy = a1.y - b1.y; dz = a1.z - b1.z; dw = a1.w - b1.w;
            s += dx * dx + dy * dy + dz * dz + dw * dw;
            dx = a2.x - b2.x; dy = a2.y - b2.y; dz = a2.z - b2.z; dw = a2.w - b2.w;
            s += dx * dx + dy * dy + dz * dz + dw * dw;
            dx = a3.x - b3.x; dy = a3.y - b3.y; dz = a3.z - b3.z; dw = a3.w - b3.w;
            s += dx * dx + dy * dy + dz * dz + dw * dw;
        }

        // 4-step butterfly reduces all four 16-lane groups in parallel
        s += __shfl_xor(s, 1, 64);
        s += __shfl_xor(s, 2, 64);
        s += __shfl_xor(s, 4, 64);
        s += __shfl_xor(s, 8, 64);

        if (valid) {
            const float dist = sqrtf(s);
            acc += is_neg ? fmaxf(0.0f, MARGIN - dist) : dist;
        }
    }

    // acc is replicated within each 16-lane group; combine the 4 groups
    acc += __shfl_xor(acc, 16, 64);
    acc += __shfl_xor(acc, 32, 64);

    __shared__ float wsum[WAVES_PER_BLOCK];
    if (lane == 0) wsum[wave_in_block] = acc;
    __syncthreads();
    if (threadIdx.x == 0) {
        float tsum = 0.0f;
        #pragma unroll
        for (int w = 0; w < WAVES_PER_BLOCK; ++w) tsum += wsum[w];
        atomicAdd(out, tsum);
    }
}

extern "C" void kernel_launch(void* const* d_in, const int* in_sizes, int n_in,
                              void* d_out, int out_size, void* d_ws, size_t ws_size,
                              hipStream_t stream) {
    const float* h = (const float*)d_in[0];
    const int* pos = (const int*)d_in[1];
    const int* neg = (const int*)d_in[2];
    float* out = (float*)d_out;

    const int P = in_sizes[1] / 2;   // 200000 pairs each

    // d_out is poisoned with 0xAA before every timed replay — zero it first.
    zero_out_kernel<<<1, 1, 0, stream>>>(out);

    // 2P = 400000 pairs; 6250 blocks * 4 waves * 4 pairs = 100000 pairs/sweep
    // -> exactly 4 balanced sweeps per wave.
    int total_pairs = 2 * P;
    int blocks = (total_pairs + WAVES_PER_BLOCK * PAIRS_PER_WAVE * 4 - 1) /
                 (WAVES_PER_BLOCK * PAIRS_PER_WAVE * 4);
    if (blocks < 1) blocks = 1;

    pair_loss_kernel<<<blocks, 256, 0, stream>>>(h, pos, neg, out, P);
}